// Round 14
// baseline (216.487 us; speedup 1.0000x reference)
//
#include <hip/hip_runtime.h>
#include <hip/hip_bf16.h>

#define BIGF 1e30f
#define TC 80   // channels
#define TN 512  // sequence length (N == M)
#define L2E 1.4426950408889634f   // log2(e)
#define LN2 0.6931471805599453f   // 1/log2(e)

typedef float f32x2 __attribute__((ext_vector_type(2)));
typedef float f32x4 __attribute__((ext_vector_type(4)));
typedef short s16x8 __attribute__((ext_vector_type(8)));
typedef __attribute__((address_space(1))) const unsigned int gu32;
typedef __attribute__((address_space(3))) unsigned int lu32;

// ---------------------------------------------------------------------------
// Kernel 1: pairwise squared distances via BF16 MFMA, skewed store, log2e.
// IDENTICAL to the verified round-12 kernel EXCEPT the store map, which is
// now per-COLUMN skew (1 DP row per pipeline): p = (jj + i) & 511.
// At sweep iteration s, wave w of sdtw reads row (s - 7w) & 511,
// cols 64w..64w+63 — one contiguous 256 B chunk per wave.
// ---------------------------------------------------------------------------
__global__ __launch_bounds__(256) void pairdist_kernel(
    const float* __restrict__ x, const float* __restrict__ y,
    float* __restrict__ F) {
  const int b  = blockIdx.z;
  const int n0 = blockIdx.x * 128;  // jj tile (A / M dim)
  const int m0 = blockIdx.y * 128;  // i tile  (B / N dim)

  __shared__ __align__(16) short Ab[128 * 128];  // bf16, 256B row stride
  __shared__ __align__(16) short Bb[128 * 128];
  __shared__ float xxs[128], yys[128];

  const float* xb = x + (size_t)b * TC * TN;
  const float* yb = y + (size_t)b * TC * TN;
  const int tid = threadIdx.x;

  auto sw = [](int row, int k) -> int {
    return (row * 256 + k * 2) ^ ((row & 7) << 4);
  };
  auto cvt = [](float f) -> unsigned short {   // RNE f32 -> bf16
    unsigned u = __float_as_uint(f);
    return (unsigned short)((u + 0x7FFFu + ((u >> 16) & 1u)) >> 16);
  };

  // Stage 12 k-octets (c=0..79 data, 80..95 exact zeros) x 128 rows x 2.
  for (int item = tid; item < 12 * 128 * 2; item += 256) {
    int arr = (item >= 12 * 128) ? 1 : 0;
    int it  = item - arr * 12 * 128;
    int oct = it >> 7, n = it & 127;
    const float* src = arr ? (yb + m0 + n) : (xb + n0 + n);
    s16x8 pk;
#pragma unroll
    for (int j = 0; j < 8; ++j) {
      int c = oct * 8 + j;
      float v = (c < TC) ? src[(size_t)c * TN] : 0.f;
      pk[j] = (short)cvt(v);
    }
    short* dst = arr ? Bb : Ab;
    *(s16x8*)((char*)dst + sw(n, oct * 8)) = pk;
  }

  // Norms fp32-exact from global (coalesced per c across the half-block).
  if (tid < 128) {
    float s = 0.f;
    for (int c = 0; c < TC; ++c) {
      float v = xb[(size_t)c * TN + n0 + tid];
      s += v * v;
    }
    xxs[tid] = s;
  } else {
    int n = tid - 128;
    float s = 0.f;
    for (int c = 0; c < TC; ++c) {
      float v = yb[(size_t)c * TN + m0 + n];
      s += v * v;
    }
    yys[n] = s;
  }
  __syncthreads();

  // MFMA main: wave (wm, wn) computes 64x64.
  const int l  = tid & 63;
  const int w  = tid >> 6;
  const int wm = (w >> 1) * 64, wn = (w & 1) * 64;
  const int fr = l & 15;          // A-row / B-col index
  const int fk = (l >> 4) * 8;    // k base within K-step

  f32x4 acc[4][4] = {};
#pragma unroll
  for (int ks = 0; ks < 3; ++ks) {
    const int k0 = ks * 32 + fk;
    s16x8 af[4], bfr[4];
#pragma unroll
    for (int ta = 0; ta < 4; ++ta)
      af[ta] = *(const s16x8*)((const char*)Ab + sw(wm + ta * 16 + fr, k0));
#pragma unroll
    for (int tq = 0; tq < 4; ++tq)
      bfr[tq] = *(const s16x8*)((const char*)Bb + sw(wn + tq * 16 + fr, k0));
#pragma unroll
    for (int ta = 0; ta < 4; ++ta)
#pragma unroll
      for (int tq = 0; tq < 4; ++tq)
        acc[ta][tq] = __builtin_amdgcn_mfma_f32_16x16x32_bf16(
            af[ta], bfr[tq], acc[ta][tq], 0, 0, 0);
  }

  // Epilogue: D-layout col=lane&15, row=(lane>>4)*4+reg; per-column skew.
  float* Fb = F + (size_t)b * TN * TN;
#pragma unroll
  for (int ta = 0; ta < 4; ++ta) {
    const int mb = wm + ta * 16 + (l >> 4) * 4;
#pragma unroll
    for (int r = 0; r < 4; ++r) {
      const int jj = n0 + mb + r;
      const float xxv = xxs[mb + r];
#pragma unroll
      for (int tq = 0; tq < 4; ++tq) {
        const int nn = wn + tq * 16 + fr;
        const int i  = m0 + nn;
        float val = (xxv + yys[nn] - 2.f * acc[ta][tq][r]) * L2E;
        int p = (jj + i) & (TN - 1);
        Fb[(size_t)p * TN + i] = val;
      }
    }
  }
}

// ---------------------------------------------------------------------------
// Kernel 2: soft-DTW, 8 WAVES PER BLOCK, ONE ROW PER LANE (32 blocks x 512).
//
// Round-13 post-mortem: 2 waves/SIMD improved per-SIMD cell throughput
// 143 -> 96 cy/cell, but 2-batches-per-block halved active CUs (net 0.75x).
// Fix: one batch per block, split over 8 waves (2/SIMD on all 32 CUs);
// lane g of wave w owns pipeline v = 64w+g = DP row v+1 (one cell/body).
//
// Schedule identical in form to the verified round-10 structure, same wave
// offset 71 = 63 (lane stagger) + 8 (mailbox block delay): col
// j = s - 71w - g + 1. Mailbox timing proof carries over: the producer
// value consumed at the consumer's final column is the producer's col 512
// exactly. 1072 iterations = 134 blocks x 8, no tail.
//
// F layout: per-column skew p = (jj + i) & 511 -> at iteration s wave w
// reads row (s - 7w) & 511, cols 64w..64w+63: one 256 B contiguous chunk
// (one width-4 global_load_lds per slot; 8 outstanding). Junk reads
// (pre-start / post-finish) are finite and absorbed bitwise by the BIG
// self-sustain. Cell math bit-identical to rounds 7-13 (absmax 0.0).
// ---------------------------------------------------------------------------
__global__ __launch_bounds__(512) __attribute__((amdgpu_waves_per_eu(2)))
void sdtw_kernel(const float* __restrict__ Ft, float* __restrict__ out) {
  const int b   = blockIdx.x;
  const int tid = threadIdx.x;
  const int g   = tid & 63;         // lane
  const int w   = tid >> 6;         // wave 0..7
  const float* Fb = Ft + (size_t)b * TN * TN;

  __shared__ float ring[8][8][64];        // per-wave 8 slots x 256 B
  __shared__ f32x4 hand[7][2][2];         // [boundary][parity][2x f32x4]

  // Init mailboxes to BIG (pre-start consumers read the boundary value).
  if (tid < 28) {
    f32x4 iv; iv[0] = BIGF; iv[1] = BIGF; iv[2] = BIGF; iv[3] = BIGF;
    ((f32x4*)hand)[tid] = iv;
  }
  __syncthreads();                  // one-time; before any DMA is in flight

  float p    = BIGF;                // R[v+1][j-1] (my row's left value)
  float up_p = (tid == 0) ? 0.f : BIGF;   // R[v][j-1]; R[0][0] = 0

  // Stage iteration u for this wave: row (u-7w)&511, cols 64w..64w+63.
  auto stage = [&](int slot, int u) {
    const float* gp =
        Fb + (size_t)((u - 7 * w) & (TN - 1)) * TN + w * 64 + g;
    __builtin_amdgcn_global_load_lds((gu32*)gp, (lu32*)&ring[w][slot][0],
                                     4, 0, 0);
  };

  const unsigned rbase =
      (unsigned)(size_t)(__attribute__((address_space(3))) float*)&ring[w][0][0];
  const unsigned hbase =
      (unsigned)(size_t)(__attribute__((address_space(3))) f32x4*)&hand[0][0][0];

  // One DP cell, bit-identical to rounds 7-13.
  auto cell = [&](float d, float r0, float r1, float r2) -> float {
    float mn, md, mx;
    asm("v_min3_f32 %0, %3, %4, %5\n\t"
        "v_med3_f32 %1, %3, %4, %5\n\t"
        "v_max3_f32 %2, %3, %4, %5"
        : "=&v"(mn), "=&v"(md), "=&v"(mx)
        : "v"(r0), "v"(r1), "v"(r2));
    float e1 = __builtin_amdgcn_exp2f(mn - md);
    float e2 = __builtin_amdgcn_exp2f(mn - mx);
    float dm = d + mn;
    float ss = (1.0f + e1) + e2;
    return dm - __builtin_amdgcn_logf(ss);
  };

  // Body: pubk = producer bottom from iter s-8 (wave-uniform; BIG for
  // wave 0 = true R[0][j] boundary). Lane g's up = lane g-1's value from
  // the previous iteration via DPP wave_shr:1; lane 0 takes pubk.
  auto body = [&](float d, float pubk) -> float {
    float upc = __int_as_float(__builtin_amdgcn_update_dpp(
        __float_as_int(pubk), __float_as_int(p), 0x138, 0xf, 0xf, false));
    float cur = cell(d, up_p, upc, p);
    up_p = upc; p = cur;
    return cur;
  };

  // Preamble: stage slots 0..7 (iters 0..7) -> 8 outstanding DMA per wave.
  stage(0, 0); stage(1, 1); stage(2, 2); stage(3, 3);
  stage(4, 4); stage(5, 5); stage(6, 6); stage(7, 7);

  float d0, d1, d2, d3, d4, d5, d6, d7;

  // Main: 134 blocks x 8 bodies = 1072 iterations exactly (s = 0..1071).
  int s = 0;
  for (int B = 0; B < 134; ++B, s += 8) {
    __builtin_amdgcn_s_barrier();   // raw: orders publish(B-1) before read
    asm volatile("s_waitcnt vmcnt(0)" ::: "memory");  // staged 1 block ago

    unsigned ad = rbase + (unsigned)(g * 4);          // my float per slot
    asm volatile(
        "ds_read_b32 %0, %8\n\t"
        "ds_read_b32 %1, %8 offset:256\n\t"
        "ds_read_b32 %2, %8 offset:512\n\t"
        "ds_read_b32 %3, %8 offset:768\n\t"
        "ds_read_b32 %4, %8 offset:1024\n\t"
        "ds_read_b32 %5, %8 offset:1280\n\t"
        "ds_read_b32 %6, %8 offset:1536\n\t"
        "ds_read_b32 %7, %8 offset:1792\n\t"
        "s_waitcnt lgkmcnt(0)"
        : "=&v"(d0), "=&v"(d1), "=&v"(d2), "=&v"(d3),
          "=&v"(d4), "=&v"(d5), "=&v"(d6), "=&v"(d7)
        : "v"(ad)
        : "memory");

    // Previous block's 8 producer values (parity (B-1)&1 == (B+1)&1).
    f32x4 pA, pB;
    if (w > 0) {
      unsigned ha = hbase + (unsigned)(((w - 1) * 2 + ((B + 1) & 1)) * 32);
      asm volatile("ds_read_b128 %0, %2\n\t"
                   "ds_read_b128 %1, %2 offset:16\n\t"
                   "s_waitcnt lgkmcnt(0)"
                   : "=&v"(pA), "=&v"(pB) : "v"(ha) : "memory");
    } else {
      pA[0] = pA[1] = pA[2] = pA[3] = BIGF;
      pB[0] = pB[1] = pB[2] = pB[3] = BIGF;
    }

    // Refill all 8 slots for the NEXT block (ds_reads above are complete).
    stage(0, s + 8);  stage(1, s + 9);
    stage(2, s + 10); stage(3, s + 11);
    stage(4, s + 12); stage(5, s + 13);
    stage(6, s + 14); stage(7, s + 15);

    f32x4 k0, k1;
    k0[0] = body(d0, pA[0]); k0[1] = body(d1, pA[1]);
    k0[2] = body(d2, pA[2]); k0[3] = body(d3, pA[3]);
    k1[0] = body(d4, pB[0]); k1[1] = body(d5, pB[1]);
    k1[2] = body(d6, pB[2]); k1[3] = body(d7, pB[3]);

    // Publish this block's 8 values for the next wave (parity B&1).
    if (w < 7 && g == 63) {
      unsigned wa = hbase + (unsigned)((w * 2 + (B & 1)) * 32);
      asm volatile("ds_write_b128 %0, %1\n\t"
                   "ds_write_b128 %0, %2 offset:16\n\t"
                   "s_waitcnt lgkmcnt(0)"
                   :: "v"(wa), "v"(k0), "v"(k1) : "memory");
    }
  }

  // R[512][512] = pipeline 511 (wave 7, lane 63) at s = 1071 (col 512).
  if (w == 7 && g == 63) out[b] = p * LN2;
}

extern "C" void kernel_launch(void* const* d_in, const int* in_sizes, int n_in,
                              void* d_out, int out_size, void* d_ws, size_t ws_size,
                              hipStream_t stream) {
  const float* x = (const float*)d_in[0];
  const float* y = (const float*)d_in[1];
  float* out = (float*)d_out;
  float* F = (float*)d_ws;  // 32*512*512*4 = 33.5 MB, per-column skew

  dim3 g1(TN / 128, TN / 128, 32);
  // Swapped args -> values are D^T (up to bf16 rounding), skewed + scaled.
  pairdist_kernel<<<g1, 256, 0, stream>>>(y, x, F);
  sdtw_kernel<<<32, 512, 0, stream>>>(F, out);
}

// Round 15
// 172.494 us; speedup vs baseline: 1.2550x; 1.2550x over previous
//
#include <hip/hip_runtime.h>
#include <hip/hip_bf16.h>

#define BIGF 1e30f
#define TC 80   // channels
#define TN 512  // sequence length (N == M)
#define L2E 1.4426950408889634f   // log2(e)
#define LN2 0.6931471805599453f   // 1/log2(e)

typedef float f32x2 __attribute__((ext_vector_type(2)));
typedef float f32x4 __attribute__((ext_vector_type(4)));
typedef short s16x8 __attribute__((ext_vector_type(8)));
typedef __attribute__((address_space(1))) const unsigned int gu32;
typedef __attribute__((address_space(3))) unsigned int lu32;

// ---------------------------------------------------------------------------
// Kernel 1: pairwise squared distances via BF16 MFMA, skewed store, log2e.
// BYTE-IDENTICAL to the verified round-12 kernel (absmax 0.0, ~83 us),
// including the store map p = (jj + (i>>1)) & 511 (round-14's (jj+i) map
// made stores fully diagonal-scattered and cost ~20 us — reverted).
// ---------------------------------------------------------------------------
__global__ __launch_bounds__(256) void pairdist_kernel(
    const float* __restrict__ x, const float* __restrict__ y,
    float* __restrict__ F) {
  const int b  = blockIdx.z;
  const int n0 = blockIdx.x * 128;  // jj tile (A / M dim)
  const int m0 = blockIdx.y * 128;  // i tile  (B / N dim)

  __shared__ __align__(16) short Ab[128 * 128];  // bf16, 256B row stride
  __shared__ __align__(16) short Bb[128 * 128];
  __shared__ float xxs[128], yys[128];

  const float* xb = x + (size_t)b * TC * TN;
  const float* yb = y + (size_t)b * TC * TN;
  const int tid = threadIdx.x;

  auto sw = [](int row, int k) -> int {
    return (row * 256 + k * 2) ^ ((row & 7) << 4);
  };
  auto cvt = [](float f) -> unsigned short {   // RNE f32 -> bf16
    unsigned u = __float_as_uint(f);
    return (unsigned short)((u + 0x7FFFu + ((u >> 16) & 1u)) >> 16);
  };

  // Stage 12 k-octets (c=0..79 data, 80..95 exact zeros) x 128 rows x 2.
  for (int item = tid; item < 12 * 128 * 2; item += 256) {
    int arr = (item >= 12 * 128) ? 1 : 0;
    int it  = item - arr * 12 * 128;
    int oct = it >> 7, n = it & 127;
    const float* src = arr ? (yb + m0 + n) : (xb + n0 + n);
    s16x8 pk;
#pragma unroll
    for (int j = 0; j < 8; ++j) {
      int c = oct * 8 + j;
      float v = (c < TC) ? src[(size_t)c * TN] : 0.f;
      pk[j] = (short)cvt(v);
    }
    short* dst = arr ? Bb : Ab;
    *(s16x8*)((char*)dst + sw(n, oct * 8)) = pk;
  }

  // Norms fp32-exact from global (coalesced per c across the half-block).
  if (tid < 128) {
    float s = 0.f;
    for (int c = 0; c < TC; ++c) {
      float v = xb[(size_t)c * TN + n0 + tid];
      s += v * v;
    }
    xxs[tid] = s;
  } else {
    int n = tid - 128;
    float s = 0.f;
    for (int c = 0; c < TC; ++c) {
      float v = yb[(size_t)c * TN + m0 + n];
      s += v * v;
    }
    yys[n] = s;
  }
  __syncthreads();

  // MFMA main: wave (wm, wn) computes 64x64.
  const int l  = tid & 63;
  const int w  = tid >> 6;
  const int wm = (w >> 1) * 64, wn = (w & 1) * 64;
  const int fr = l & 15;          // A-row / B-col index
  const int fk = (l >> 4) * 8;    // k base within K-step

  f32x4 acc[4][4] = {};
#pragma unroll
  for (int ks = 0; ks < 3; ++ks) {
    const int k0 = ks * 32 + fk;
    s16x8 af[4], bfr[4];
#pragma unroll
    for (int ta = 0; ta < 4; ++ta)
      af[ta] = *(const s16x8*)((const char*)Ab + sw(wm + ta * 16 + fr, k0));
#pragma unroll
    for (int tq = 0; tq < 4; ++tq)
      bfr[tq] = *(const s16x8*)((const char*)Bb + sw(wn + tq * 16 + fr, k0));
#pragma unroll
    for (int ta = 0; ta < 4; ++ta)
#pragma unroll
      for (int tq = 0; tq < 4; ++tq)
        acc[ta][tq] = __builtin_amdgcn_mfma_f32_16x16x32_bf16(
            af[ta], bfr[tq], acc[ta][tq], 0, 0, 0);
  }

  // Epilogue: D-layout col=lane&15, row=(lane>>4)*4+reg; skewed scalar
  // stores, identical mapping/expression to the verified round-12 kernel.
  float* Fb = F + (size_t)b * TN * TN;
#pragma unroll
  for (int ta = 0; ta < 4; ++ta) {
    const int mb = wm + ta * 16 + (l >> 4) * 4;
#pragma unroll
    for (int r = 0; r < 4; ++r) {
      const int jj = n0 + mb + r;
      const float xxv = xxs[mb + r];
#pragma unroll
      for (int tq = 0; tq < 4; ++tq) {
        const int nn = wn + tq * 16 + fr;
        const int i  = m0 + nn;
        float val = (xxv + yys[nn] - 2.f * acc[ta][tq][r]) * L2E;
        int p = (jj + (i >> 1)) & (TN - 1);
        Fb[(size_t)p * TN + i] = val;
      }
    }
  }
}

// ---------------------------------------------------------------------------
// Kernel 2: soft-DTW, round-12 structure (32 blocks x 4 waves, 2 rows/lane)
// with BLOCK LENGTH 16 (was 8) to halve the per-block serial overhead's
// per-iteration share (round-12 accounting: 287 cy/iter = ~130 chain +
// ~150 block-top overhead).
//
// Mechanical deltas from the verified round-10/12 algebra (delay 8 -> 16):
//   wave offset 71 -> 79 (= 63 + 16);  col j = s - 79w - g + 1
//   stage row (u - 7w) -> (u - 15w)  [p = (j-1) + v = s - 15w mod 512]
//   ring 8 -> 16 slots/wave (32 KB);  mailbox 16 values/parity (4x b128)
//   iterations 788 -> 812 = 50 x 16 + 12 tail
// Handoff timing re-derived: producer (w-1, lane63) col at iter s' is
// s' - 79w + 17; consumer (w, lane0) needs col s - 79w + 1 -> s' = s - 16 =
// previous block exactly. Parity double-buffer as before. Cell math
// bit-identical to rounds 7-14 (absmax 0.0).
// ---------------------------------------------------------------------------
__global__ __launch_bounds__(256) __attribute__((amdgpu_waves_per_eu(1)))
void sdtw_kernel(const float* __restrict__ Ft, float* __restrict__ out) {
  const int b   = blockIdx.x;
  const int tid = threadIdx.x;
  const int g   = tid & 63;         // lane
  const int w   = tid >> 6;         // wave 0..3
  const float* Fb = Ft + (size_t)b * TN * TN;

  __shared__ float ring[4][16][128];      // per-wave 16 slots x 512 B
  __shared__ f32x4 hand[3][2][4];         // [boundary][parity][16 floats]

  // Init mailboxes to BIG (pre-start consumers read the boundary value).
  if (tid < 24) {
    f32x4 iv; iv[0] = BIGF; iv[1] = BIGF; iv[2] = BIGF; iv[3] = BIGF;
    ((f32x4*)hand)[tid] = iv;
  }
  __syncthreads();                  // one-time; before any DMA is in flight

  float p0 = BIGF, p1 = BIGF;       // left values of my 2 rows
  float up_p = (tid == 0) ? 0.f : BIGF;   // R[2v][j-1]; R[0][0] = 0

  // Stage iteration u for this wave: row (u-15w)&511, cols 128w..128w+127.
  auto stage = [&](int slot, int u) {
    const float* gp =
        Fb + (size_t)((u - 15 * w) & (TN - 1)) * TN + w * 128 + g;
    __builtin_amdgcn_global_load_lds((gu32*)gp,        (lu32*)&ring[w][slot][0],  4, 0, 0);
    __builtin_amdgcn_global_load_lds((gu32*)(gp + 64), (lu32*)&ring[w][slot][64], 4, 0, 0);
  };

  const unsigned rbase =
      (unsigned)(size_t)(__attribute__((address_space(3))) float*)&ring[w][0][0];
  const unsigned hbase =
      (unsigned)(size_t)(__attribute__((address_space(3))) f32x4*)&hand[0][0][0];

  // One DP cell, bit-identical to rounds 7-14.
  auto cell = [&](float d, float r0, float r1, float r2) -> float {
    float mn, md, mx;
    asm("v_min3_f32 %0, %3, %4, %5\n\t"
        "v_med3_f32 %1, %3, %4, %5\n\t"
        "v_max3_f32 %2, %3, %4, %5"
        : "=&v"(mn), "=&v"(md), "=&v"(mx)
        : "v"(r0), "v"(r1), "v"(r2));
    float e1 = __builtin_amdgcn_exp2f(mn - md);
    float e2 = __builtin_amdgcn_exp2f(mn - mx);
    float dm = d + mn;
    float ss = (1.0f + e1) + e2;
    return dm - __builtin_amdgcn_logf(ss);
  };

  // Body: pubk = producer bottom from iter s-16 (wave-uniform broadcast;
  // BIG for wave 0). Lane g's up value comes from lane g-1 (1-iter delay)
  // via DPP wave_shr:1; lane 0 takes pubk. Returns my bottom (for publish).
  auto body = [&](f32x2 d, float pubk) -> float {
    float upc = __int_as_float(__builtin_amdgcn_update_dpp(
        __float_as_int(pubk), __float_as_int(p1), 0x138, 0xf, 0xf, false));
    float c0 = cell(d[0], up_p, upc, p0);   // top row
    float c1 = cell(d[1], p0, c0, p1);      // bottom row
    p0 = c0; p1 = c1; up_p = upc;
    return c1;
  };

  // Preamble: stage slots 0..15 (iters 0..15) -> 32 outstanding DMA/wave.
#pragma unroll
  for (int sl = 0; sl < 16; ++sl) stage(sl, sl);

  f32x2 d0, d1, d2, d3, d4, d5, d6, d7;
  f32x2 d8, d9, d10, d11, d12, d13, d14, d15;

  // Main: 50 blocks x 16 bodies (iters 0..799).
  int s = 0;
  for (int B = 0; B < 50; ++B, s += 16) {
    __builtin_amdgcn_s_barrier();   // raw: orders publish(B-1) before read
    asm volatile("s_waitcnt vmcnt(0)" ::: "memory");  // staged 1 block ago

    unsigned ad = rbase + (unsigned)(g * 8);          // my float2 per slot
    asm volatile(
        "ds_read_b64 %0, %16\n\t"
        "ds_read_b64 %1, %16 offset:512\n\t"
        "ds_read_b64 %2, %16 offset:1024\n\t"
        "ds_read_b64 %3, %16 offset:1536\n\t"
        "ds_read_b64 %4, %16 offset:2048\n\t"
        "ds_read_b64 %5, %16 offset:2560\n\t"
        "ds_read_b64 %6, %16 offset:3072\n\t"
        "ds_read_b64 %7, %16 offset:3584\n\t"
        "ds_read_b64 %8, %16 offset:4096\n\t"
        "ds_read_b64 %9, %16 offset:4608\n\t"
        "ds_read_b64 %10, %16 offset:5120\n\t"
        "ds_read_b64 %11, %16 offset:5632\n\t"
        "ds_read_b64 %12, %16 offset:6144\n\t"
        "ds_read_b64 %13, %16 offset:6656\n\t"
        "ds_read_b64 %14, %16 offset:7168\n\t"
        "ds_read_b64 %15, %16 offset:7680\n\t"
        "s_waitcnt lgkmcnt(0)"
        : "=&v"(d0), "=&v"(d1), "=&v"(d2), "=&v"(d3),
          "=&v"(d4), "=&v"(d5), "=&v"(d6), "=&v"(d7),
          "=&v"(d8), "=&v"(d9), "=&v"(d10), "=&v"(d11),
          "=&v"(d12), "=&v"(d13), "=&v"(d14), "=&v"(d15)
        : "v"(ad)
        : "memory");

    // Previous block's 16 producer bottoms (parity (B-1)&1 == (B+1)&1).
    f32x4 pA, pB, pC, pD;
    if (w > 0) {
      unsigned ha = hbase + (unsigned)(((w - 1) * 2 + ((B + 1) & 1)) * 64);
      asm volatile("ds_read_b128 %0, %4\n\t"
                   "ds_read_b128 %1, %4 offset:16\n\t"
                   "ds_read_b128 %2, %4 offset:32\n\t"
                   "ds_read_b128 %3, %4 offset:48\n\t"
                   "s_waitcnt lgkmcnt(0)"
                   : "=&v"(pA), "=&v"(pB), "=&v"(pC), "=&v"(pD)
                   : "v"(ha) : "memory");
    } else {
      pA[0] = pA[1] = pA[2] = pA[3] = BIGF;
      pB[0] = pB[1] = pB[2] = pB[3] = BIGF;
      pC[0] = pC[1] = pC[2] = pC[3] = BIGF;
      pD[0] = pD[1] = pD[2] = pD[3] = BIGF;
    }

    // Refill all 16 slots for the NEXT block (reads above are complete).
#pragma unroll
    for (int sl = 0; sl < 16; ++sl) stage(sl, s + 16 + sl);

    f32x4 k0, k1, k2, k3;
    k0[0] = body(d0, pA[0]);  k0[1] = body(d1, pA[1]);
    k0[2] = body(d2, pA[2]);  k0[3] = body(d3, pA[3]);
    k1[0] = body(d4, pB[0]);  k1[1] = body(d5, pB[1]);
    k1[2] = body(d6, pB[2]);  k1[3] = body(d7, pB[3]);
    k2[0] = body(d8, pC[0]);  k2[1] = body(d9, pC[1]);
    k2[2] = body(d10, pC[2]); k2[3] = body(d11, pC[3]);
    k3[0] = body(d12, pD[0]); k3[1] = body(d13, pD[1]);
    k3[2] = body(d14, pD[2]); k3[3] = body(d15, pD[3]);

    // Publish this block's 16 bottoms for the next wave (parity B&1).
    if (w < 3 && g == 63) {
      unsigned wa = hbase + (unsigned)((w * 2 + (B & 1)) * 64);
      asm volatile("ds_write_b128 %0, %1\n\t"
                   "ds_write_b128 %0, %2 offset:16\n\t"
                   "ds_write_b128 %0, %3 offset:32\n\t"
                   "ds_write_b128 %0, %4 offset:48\n\t"
                   "s_waitcnt lgkmcnt(0)"
                   :: "v"(wa), "v"(k0), "v"(k1), "v"(k2), "v"(k3)
                   : "memory");
    }
  }

  // Tail: iters 800..811 (12 bodies, slots 0..11, staged during block 49).
  __builtin_amdgcn_s_barrier();
  asm volatile("s_waitcnt vmcnt(0)" ::: "memory");
  {
    unsigned ad = rbase + (unsigned)(g * 8);
    asm volatile(
        "ds_read_b64 %0, %12\n\t"
        "ds_read_b64 %1, %12 offset:512\n\t"
        "ds_read_b64 %2, %12 offset:1024\n\t"
        "ds_read_b64 %3, %12 offset:1536\n\t"
        "ds_read_b64 %4, %12 offset:2048\n\t"
        "ds_read_b64 %5, %12 offset:2560\n\t"
        "ds_read_b64 %6, %12 offset:3072\n\t"
        "ds_read_b64 %7, %12 offset:3584\n\t"
        "ds_read_b64 %8, %12 offset:4096\n\t"
        "ds_read_b64 %9, %12 offset:4608\n\t"
        "ds_read_b64 %10, %12 offset:5120\n\t"
        "ds_read_b64 %11, %12 offset:5632\n\t"
        "s_waitcnt lgkmcnt(0)"
        : "=&v"(d0), "=&v"(d1), "=&v"(d2), "=&v"(d3),
          "=&v"(d4), "=&v"(d5), "=&v"(d6), "=&v"(d7),
          "=&v"(d8), "=&v"(d9), "=&v"(d10), "=&v"(d11)
        : "v"(ad)
        : "memory");
  }
  f32x4 pA, pB, pC;
  if (w > 0) {
    // Producer block-49 values (parity 49&1 = 1); need positions 0..11.
    unsigned ha = hbase + (unsigned)(((w - 1) * 2 + 1) * 64);
    asm volatile("ds_read_b128 %0, %3\n\t"
                 "ds_read_b128 %1, %3 offset:16\n\t"
                 "ds_read_b128 %2, %3 offset:32\n\t"
                 "s_waitcnt lgkmcnt(0)"
                 : "=&v"(pA), "=&v"(pB), "=&v"(pC) : "v"(ha) : "memory");
  } else {
    pA[0] = pA[1] = pA[2] = pA[3] = BIGF;
    pB[0] = pB[1] = pB[2] = pB[3] = BIGF;
    pC[0] = pC[1] = pC[2] = pC[3] = BIGF;
  }
  body(d0, pA[0]);  body(d1, pA[1]);  body(d2, pA[2]);  body(d3, pA[3]);
  body(d4, pB[0]);  body(d5, pB[1]);  body(d6, pB[2]);  body(d7, pB[3]);
  body(d8, pC[0]);  body(d9, pC[1]);  body(d10, pC[2]); body(d11, pC[3]);

  // R[512][512] = pipeline 255 (wave 3, lane 63) bottom row at s = 811.
  if (w == 3 && g == 63) out[b] = p1 * LN2;
}

extern "C" void kernel_launch(void* const* d_in, const int* in_sizes, int n_in,
                              void* d_out, int out_size, void* d_ws, size_t ws_size,
                              hipStream_t stream) {
  const float* x = (const float*)d_in[0];
  const float* y = (const float*)d_in[1];
  float* out = (float*)d_out;
  float* F = (float*)d_ws;  // 32*512*512*4 = 33.5 MB, skewed layout

  dim3 g1(TN / 128, TN / 128, 32);
  // Swapped args -> values are D^T (up to bf16 rounding), skewed + scaled.
  pairdist_kernel<<<g1, 256, 0, stream>>>(y, x, F);
  sdtw_kernel<<<32, 256, 0, stream>>>(F, out);
}

// Round 16
// 158.301 us; speedup vs baseline: 1.3676x; 1.0897x over previous
//
#include <hip/hip_runtime.h>
#include <hip/hip_bf16.h>

#define BIGF 1e30f
#define TC 80   // channels
#define TN 512  // sequence length (N == M)
#define L2E 1.4426950408889634f   // log2(e)
#define LN2 0.6931471805599453f   // 1/log2(e)

typedef float f32x2 __attribute__((ext_vector_type(2)));
typedef float f32x4 __attribute__((ext_vector_type(4)));
typedef short s16x8 __attribute__((ext_vector_type(8)));
typedef __attribute__((address_space(1))) const unsigned int gu32;
typedef __attribute__((address_space(3))) unsigned int lu32;

// ---------------------------------------------------------------------------
// Kernel 1: pairwise squared distances via BF16 MFMA, skewed store, log2e.
// BYTE-IDENTICAL to the verified round-12/15 kernel (absmax 0.0, ~85 us).
// ---------------------------------------------------------------------------
__global__ __launch_bounds__(256) void pairdist_kernel(
    const float* __restrict__ x, const float* __restrict__ y,
    float* __restrict__ F) {
  const int b  = blockIdx.z;
  const int n0 = blockIdx.x * 128;  // jj tile (A / M dim)
  const int m0 = blockIdx.y * 128;  // i tile  (B / N dim)

  __shared__ __align__(16) short Ab[128 * 128];  // bf16, 256B row stride
  __shared__ __align__(16) short Bb[128 * 128];
  __shared__ float xxs[128], yys[128];

  const float* xb = x + (size_t)b * TC * TN;
  const float* yb = y + (size_t)b * TC * TN;
  const int tid = threadIdx.x;

  auto sw = [](int row, int k) -> int {
    return (row * 256 + k * 2) ^ ((row & 7) << 4);
  };
  auto cvt = [](float f) -> unsigned short {   // RNE f32 -> bf16
    unsigned u = __float_as_uint(f);
    return (unsigned short)((u + 0x7FFFu + ((u >> 16) & 1u)) >> 16);
  };

  // Stage 12 k-octets (c=0..79 data, 80..95 exact zeros) x 128 rows x 2.
  for (int item = tid; item < 12 * 128 * 2; item += 256) {
    int arr = (item >= 12 * 128) ? 1 : 0;
    int it  = item - arr * 12 * 128;
    int oct = it >> 7, n = it & 127;
    const float* src = arr ? (yb + m0 + n) : (xb + n0 + n);
    s16x8 pk;
#pragma unroll
    for (int j = 0; j < 8; ++j) {
      int c = oct * 8 + j;
      float v = (c < TC) ? src[(size_t)c * TN] : 0.f;
      pk[j] = (short)cvt(v);
    }
    short* dst = arr ? Bb : Ab;
    *(s16x8*)((char*)dst + sw(n, oct * 8)) = pk;
  }

  // Norms fp32-exact from global (coalesced per c across the half-block).
  if (tid < 128) {
    float s = 0.f;
    for (int c = 0; c < TC; ++c) {
      float v = xb[(size_t)c * TN + n0 + tid];
      s += v * v;
    }
    xxs[tid] = s;
  } else {
    int n = tid - 128;
    float s = 0.f;
    for (int c = 0; c < TC; ++c) {
      float v = yb[(size_t)c * TN + m0 + n];
      s += v * v;
    }
    yys[n] = s;
  }
  __syncthreads();

  // MFMA main: wave (wm, wn) computes 64x64.
  const int l  = tid & 63;
  const int w  = tid >> 6;
  const int wm = (w >> 1) * 64, wn = (w & 1) * 64;
  const int fr = l & 15;          // A-row / B-col index
  const int fk = (l >> 4) * 8;    // k base within K-step

  f32x4 acc[4][4] = {};
#pragma unroll
  for (int ks = 0; ks < 3; ++ks) {
    const int k0 = ks * 32 + fk;
    s16x8 af[4], bfr[4];
#pragma unroll
    for (int ta = 0; ta < 4; ++ta)
      af[ta] = *(const s16x8*)((const char*)Ab + sw(wm + ta * 16 + fr, k0));
#pragma unroll
    for (int tq = 0; tq < 4; ++tq)
      bfr[tq] = *(const s16x8*)((const char*)Bb + sw(wn + tq * 16 + fr, k0));
#pragma unroll
    for (int ta = 0; ta < 4; ++ta)
#pragma unroll
      for (int tq = 0; tq < 4; ++tq)
        acc[ta][tq] = __builtin_amdgcn_mfma_f32_16x16x32_bf16(
            af[ta], bfr[tq], acc[ta][tq], 0, 0, 0);
  }

  // Epilogue: D-layout col=lane&15, row=(lane>>4)*4+reg; skewed scalar
  // stores, identical mapping/expression to the verified round-12 kernel.
  float* Fb = F + (size_t)b * TN * TN;
#pragma unroll
  for (int ta = 0; ta < 4; ++ta) {
    const int mb = wm + ta * 16 + (l >> 4) * 4;
#pragma unroll
    for (int r = 0; r < 4; ++r) {
      const int jj = n0 + mb + r;
      const float xxv = xxs[mb + r];
#pragma unroll
      for (int tq = 0; tq < 4; ++tq) {
        const int nn = wn + tq * 16 + fr;
        const int i  = m0 + nn;
        float val = (xxv + yys[nn] - 2.f * acc[ta][tq][r]) * L2E;
        int p = (jj + (i >> 1)) & (TN - 1);
        Fb[(size_t)p * TN + i] = val;
      }
    }
  }
}

// ---------------------------------------------------------------------------
// Kernel 2: soft-DTW, round-12/15 structure (32 blocks x 4 waves, 2 rows
// per lane) with BLOCK LENGTH 32 (was 16) + PAIRED width-16 staging.
//
// Round-15 confirmed the block-top overhead model (~1000 cy/block serial);
// at length 32 its per-iteration share drops to ~16 cy. Deltas from the
// verified delay-16 algebra (delay 16 -> 32):
//   wave offset 79 -> 95 (= 63 + 32);  col j = s - 95w - g + 1
//   stage row (u - 15w) -> (u - 31w)
//   ring 16 -> 32 slots/wave (64 KB); mailbox 32 values/parity (8x b128)
//   iterations 812 -> 860 = 26 x 32 + 28 tail
// Handoff: consumer (w, lane0) at iter s needs producer col s - 95w + 1;
// producer (w-1, lane63) computed it at iter s-32 = previous block exactly.
//
// Paired staging: one width-16 global_load_lds stages TWO slots (lanes
// 0-31 -> slot 2k from row (u0-31w), lanes 32-63 -> slot 2k+1 from row
// (u0+1-31w)); per-lane global source, uniform LDS base + lane*16 spans
// the two contiguous 512 B slots. 16 DMA issues per 32 iters (was 64).
// Read-before-refill: each 16-slot ds_read batch completes (lgkmcnt(0)
// inside the asm) before its slots are re-staged. Max 16 DMA outstanding.
// Cell math bit-identical to rounds 7-15 (absmax 0.0).
// ---------------------------------------------------------------------------
__global__ __launch_bounds__(256) __attribute__((amdgpu_waves_per_eu(1)))
void sdtw_kernel(const float* __restrict__ Ft, float* __restrict__ out) {
  const int b   = blockIdx.x;
  const int tid = threadIdx.x;
  const int g   = tid & 63;         // lane
  const int w   = tid >> 6;         // wave 0..3
  const float* Fb = Ft + (size_t)b * TN * TN;

  __shared__ float ring[4][32][128];      // per-wave 32 slots x 512 B
  __shared__ f32x4 hand[3][2][8];         // [boundary][parity][32 floats]

  // Init mailboxes to BIG (pre-start consumers read the boundary value).
  if (tid < 48) {
    f32x4 iv; iv[0] = BIGF; iv[1] = BIGF; iv[2] = BIGF; iv[3] = BIGF;
    ((f32x4*)hand)[tid] = iv;
  }
  __syncthreads();                  // one-time; before any DMA is in flight

  float p0 = BIGF, p1 = BIGF;       // left values of my 2 rows
  float up_p = (tid == 0) ? 0.f : BIGF;   // R[2v][j-1]; R[0][0] = 0

  // Paired stage: slots 2k (iter u0) and 2k+1 (iter u0+1) in ONE width-16
  // DMA. Lane l<32 sources row (u0-31w), floats 4l..4l+3; lane l>=32 the
  // same for u0+1. LDS dest = uniform base + lane*16 fills the contiguous
  // 1 KB of the two slots.
  auto stage2 = [&](int k, int u0) {
    int u = u0 + (g >> 5);
    const float* gp =
        Fb + (size_t)((u - 31 * w) & (TN - 1)) * TN + w * 128 + (g & 31) * 4;
    __builtin_amdgcn_global_load_lds((gu32*)gp, (lu32*)&ring[w][k * 2][0],
                                     16, 0, 0);
  };

  const unsigned rbase =
      (unsigned)(size_t)(__attribute__((address_space(3))) float*)&ring[w][0][0];
  const unsigned hbase =
      (unsigned)(size_t)(__attribute__((address_space(3))) f32x4*)&hand[0][0][0];

  // One DP cell, bit-identical to rounds 7-15.
  auto cell = [&](float d, float r0, float r1, float r2) -> float {
    float mn, md, mx;
    asm("v_min3_f32 %0, %3, %4, %5\n\t"
        "v_med3_f32 %1, %3, %4, %5\n\t"
        "v_max3_f32 %2, %3, %4, %5"
        : "=&v"(mn), "=&v"(md), "=&v"(mx)
        : "v"(r0), "v"(r1), "v"(r2));
    float e1 = __builtin_amdgcn_exp2f(mn - md);
    float e2 = __builtin_amdgcn_exp2f(mn - mx);
    float dm = d + mn;
    float ss = (1.0f + e1) + e2;
    return dm - __builtin_amdgcn_logf(ss);
  };

  // Body: pubk = producer bottom from iter s-32 (wave-uniform broadcast;
  // BIG for wave 0). Lane g's up value comes from lane g-1 (1-iter delay)
  // via DPP wave_shr:1; lane 0 takes pubk. Returns my bottom (for publish).
  auto body = [&](f32x2 d, float pubk) -> float {
    float upc = __int_as_float(__builtin_amdgcn_update_dpp(
        __float_as_int(pubk), __float_as_int(p1), 0x138, 0xf, 0xf, false));
    float c0 = cell(d[0], up_p, upc, p0);   // top row
    float c1 = cell(d[1], p0, c0, p1);      // bottom row
    p0 = c0; p1 = c1; up_p = upc;
    return c1;
  };

  // 16-slot batched read: slots [base16*16 .. +15], my float2 per slot.
  f32x2 d0, d1, d2, d3, d4, d5, d6, d7;
  f32x2 d8, d9, d10, d11, d12, d13, d14, d15;
  auto read16 = [&](int base16) {
    unsigned ad = rbase + (unsigned)(base16 * 8192) + (unsigned)(g * 8);
    asm volatile(
        "ds_read_b64 %0, %16\n\t"
        "ds_read_b64 %1, %16 offset:512\n\t"
        "ds_read_b64 %2, %16 offset:1024\n\t"
        "ds_read_b64 %3, %16 offset:1536\n\t"
        "ds_read_b64 %4, %16 offset:2048\n\t"
        "ds_read_b64 %5, %16 offset:2560\n\t"
        "ds_read_b64 %6, %16 offset:3072\n\t"
        "ds_read_b64 %7, %16 offset:3584\n\t"
        "ds_read_b64 %8, %16 offset:4096\n\t"
        "ds_read_b64 %9, %16 offset:4608\n\t"
        "ds_read_b64 %10, %16 offset:5120\n\t"
        "ds_read_b64 %11, %16 offset:5632\n\t"
        "ds_read_b64 %12, %16 offset:6144\n\t"
        "ds_read_b64 %13, %16 offset:6656\n\t"
        "ds_read_b64 %14, %16 offset:7168\n\t"
        "ds_read_b64 %15, %16 offset:7680\n\t"
        "s_waitcnt lgkmcnt(0)"
        : "=&v"(d0), "=&v"(d1), "=&v"(d2), "=&v"(d3),
          "=&v"(d4), "=&v"(d5), "=&v"(d6), "=&v"(d7),
          "=&v"(d8), "=&v"(d9), "=&v"(d10), "=&v"(d11),
          "=&v"(d12), "=&v"(d13), "=&v"(d14), "=&v"(d15)
        : "v"(ad)
        : "memory");
  };

  // Preamble: stage slots 0..31 (iters 0..31) -> 16 outstanding DMA/wave.
#pragma unroll
  for (int k = 0; k < 16; ++k) stage2(k, 2 * k);

  // Main: 26 blocks x 32 bodies (iters 0..831).
  int s = 0;
  for (int B = 0; B < 26; ++B, s += 32) {
    __builtin_amdgcn_s_barrier();   // raw: orders publish(B-1) before read
    asm volatile("s_waitcnt vmcnt(0)" ::: "memory");  // staged 1 block ago

    // Previous block's 32 producer bottoms (parity (B-1)&1 == (B+1)&1).
    f32x4 m0, m1, m2, m3, m4, m5, m6, m7;
    if (w > 0) {
      unsigned ha = hbase + (unsigned)(((w - 1) * 2 + ((B + 1) & 1)) * 128);
      asm volatile("ds_read_b128 %0, %8\n\t"
                   "ds_read_b128 %1, %8 offset:16\n\t"
                   "ds_read_b128 %2, %8 offset:32\n\t"
                   "ds_read_b128 %3, %8 offset:48\n\t"
                   "ds_read_b128 %4, %8 offset:64\n\t"
                   "ds_read_b128 %5, %8 offset:80\n\t"
                   "ds_read_b128 %6, %8 offset:96\n\t"
                   "ds_read_b128 %7, %8 offset:112\n\t"
                   "s_waitcnt lgkmcnt(0)"
                   : "=&v"(m0), "=&v"(m1), "=&v"(m2), "=&v"(m3),
                     "=&v"(m4), "=&v"(m5), "=&v"(m6), "=&v"(m7)
                   : "v"(ha) : "memory");
    } else {
      m0[0]=m0[1]=m0[2]=m0[3]=BIGF; m1[0]=m1[1]=m1[2]=m1[3]=BIGF;
      m2[0]=m2[1]=m2[2]=m2[3]=BIGF; m3[0]=m3[1]=m3[2]=m3[3]=BIGF;
      m4[0]=m4[1]=m4[2]=m4[3]=BIGF; m5[0]=m5[1]=m5[2]=m5[3]=BIGF;
      m6[0]=m6[1]=m6[2]=m6[3]=BIGF; m7[0]=m7[1]=m7[2]=m7[3]=BIGF;
    }

    f32x4 k0, k1, k2, k3, k4, k5, k6, k7;

    // Sub-block A: read slots 0..15 (completes), refill them, 16 bodies.
    read16(0);
#pragma unroll
    for (int k = 0; k < 8; ++k) stage2(k, s + 32 + 2 * k);
    k0[0] = body(d0, m0[0]);  k0[1] = body(d1, m0[1]);
    k0[2] = body(d2, m0[2]);  k0[3] = body(d3, m0[3]);
    k1[0] = body(d4, m1[0]);  k1[1] = body(d5, m1[1]);
    k1[2] = body(d6, m1[2]);  k1[3] = body(d7, m1[3]);
    k2[0] = body(d8, m2[0]);  k2[1] = body(d9, m2[1]);
    k2[2] = body(d10, m2[2]); k2[3] = body(d11, m2[3]);
    k3[0] = body(d12, m3[0]); k3[1] = body(d13, m3[1]);
    k3[2] = body(d14, m3[2]); k3[3] = body(d15, m3[3]);

    // Sub-block B: read slots 16..31, refill them, 16 bodies.
    read16(1);
#pragma unroll
    for (int k = 8; k < 16; ++k) stage2(k, s + 32 + 2 * k);
    k4[0] = body(d0, m4[0]);  k4[1] = body(d1, m4[1]);
    k4[2] = body(d2, m4[2]);  k4[3] = body(d3, m4[3]);
    k5[0] = body(d4, m5[0]);  k5[1] = body(d5, m5[1]);
    k5[2] = body(d6, m5[2]);  k5[3] = body(d7, m5[3]);
    k6[0] = body(d8, m6[0]);  k6[1] = body(d9, m6[1]);
    k6[2] = body(d10, m6[2]); k6[3] = body(d11, m6[3]);
    k7[0] = body(d12, m7[0]); k7[1] = body(d13, m7[1]);
    k7[2] = body(d14, m7[2]); k7[3] = body(d15, m7[3]);

    // Publish this block's 32 bottoms for the next wave (parity B&1).
    if (w < 3 && g == 63) {
      unsigned wa = hbase + (unsigned)((w * 2 + (B & 1)) * 128);
      asm volatile("ds_write_b128 %0, %1\n\t"
                   "ds_write_b128 %0, %2 offset:16\n\t"
                   "ds_write_b128 %0, %3 offset:32\n\t"
                   "ds_write_b128 %0, %4 offset:48\n\t"
                   "ds_write_b128 %0, %5 offset:64\n\t"
                   "ds_write_b128 %0, %6 offset:80\n\t"
                   "ds_write_b128 %0, %7 offset:96\n\t"
                   "ds_write_b128 %0, %8 offset:112\n\t"
                   "s_waitcnt lgkmcnt(0)"
                   :: "v"(wa), "v"(k0), "v"(k1), "v"(k2), "v"(k3),
                      "v"(k4), "v"(k5), "v"(k6), "v"(k7)
                   : "memory");
    }
  }

  // Tail: iters 832..859 (28 bodies, slots 0..27, staged during block 25;
  // producer values = block 25's publish, parity 25&1 = 1).
  __builtin_amdgcn_s_barrier();
  asm volatile("s_waitcnt vmcnt(0)" ::: "memory");
  f32x4 m0, m1, m2, m3, m4, m5, m6;
  if (w > 0) {
    unsigned ha = hbase + (unsigned)(((w - 1) * 2 + 1) * 128);
    asm volatile("ds_read_b128 %0, %7\n\t"
                 "ds_read_b128 %1, %7 offset:16\n\t"
                 "ds_read_b128 %2, %7 offset:32\n\t"
                 "ds_read_b128 %3, %7 offset:48\n\t"
                 "ds_read_b128 %4, %7 offset:64\n\t"
                 "ds_read_b128 %5, %7 offset:80\n\t"
                 "ds_read_b128 %6, %7 offset:96\n\t"
                 "s_waitcnt lgkmcnt(0)"
                 : "=&v"(m0), "=&v"(m1), "=&v"(m2), "=&v"(m3),
                   "=&v"(m4), "=&v"(m5), "=&v"(m6)
                 : "v"(ha) : "memory");
  } else {
    m0[0]=m0[1]=m0[2]=m0[3]=BIGF; m1[0]=m1[1]=m1[2]=m1[3]=BIGF;
    m2[0]=m2[1]=m2[2]=m2[3]=BIGF; m3[0]=m3[1]=m3[2]=m3[3]=BIGF;
    m4[0]=m4[1]=m4[2]=m4[3]=BIGF; m5[0]=m5[1]=m5[2]=m5[3]=BIGF;
    m6[0]=m6[1]=m6[2]=m6[3]=BIGF;
  }

  read16(0);                         // slots 0..15 = iters 832..847
  body(d0, m0[0]);  body(d1, m0[1]);  body(d2, m0[2]);  body(d3, m0[3]);
  body(d4, m1[0]);  body(d5, m1[1]);  body(d6, m1[2]);  body(d7, m1[3]);
  body(d8, m2[0]);  body(d9, m2[1]);  body(d10, m2[2]); body(d11, m2[3]);
  body(d12, m3[0]); body(d13, m3[1]); body(d14, m3[2]); body(d15, m3[3]);

  {                                  // slots 16..27 = iters 848..859
    unsigned ad = rbase + 8192u + (unsigned)(g * 8);
    asm volatile(
        "ds_read_b64 %0, %12\n\t"
        "ds_read_b64 %1, %12 offset:512\n\t"
        "ds_read_b64 %2, %12 offset:1024\n\t"
        "ds_read_b64 %3, %12 offset:1536\n\t"
        "ds_read_b64 %4, %12 offset:2048\n\t"
        "ds_read_b64 %5, %12 offset:2560\n\t"
        "ds_read_b64 %6, %12 offset:3072\n\t"
        "ds_read_b64 %7, %12 offset:3584\n\t"
        "ds_read_b64 %8, %12 offset:4096\n\t"
        "ds_read_b64 %9, %12 offset:4608\n\t"
        "ds_read_b64 %10, %12 offset:5120\n\t"
        "ds_read_b64 %11, %12 offset:5632\n\t"
        "s_waitcnt lgkmcnt(0)"
        : "=&v"(d0), "=&v"(d1), "=&v"(d2), "=&v"(d3),
          "=&v"(d4), "=&v"(d5), "=&v"(d6), "=&v"(d7),
          "=&v"(d8), "=&v"(d9), "=&v"(d10), "=&v"(d11)
        : "v"(ad)
        : "memory");
  }
  body(d0, m4[0]);  body(d1, m4[1]);  body(d2, m4[2]);  body(d3, m4[3]);
  body(d4, m5[0]);  body(d5, m5[1]);  body(d6, m5[2]);  body(d7, m5[3]);
  body(d8, m6[0]);  body(d9, m6[1]);  body(d10, m6[2]); body(d11, m6[3]);

  // R[512][512] = pipeline 255 (wave 3, lane 63) bottom row at s = 859.
  if (w == 3 && g == 63) out[b] = p1 * LN2;
}

extern "C" void kernel_launch(void* const* d_in, const int* in_sizes, int n_in,
                              void* d_out, int out_size, void* d_ws, size_t ws_size,
                              hipStream_t stream) {
  const float* x = (const float*)d_in[0];
  const float* y = (const float*)d_in[1];
  float* out = (float*)d_out;
  float* F = (float*)d_ws;  // 32*512*512*4 = 33.5 MB, skewed layout

  dim3 g1(TN / 128, TN / 128, 32);
  // Swapped args -> values are D^T (up to bf16 rounding), skewed + scaled.
  pairdist_kernel<<<g1, 256, 0, stream>>>(y, x, F);
  sdtw_kernel<<<32, 256, 0, stream>>>(F, out);
}